// Round 1
// baseline (148.791 us; speedup 1.0000x reference)
//
#include <hip/hip_runtime.h>
#include <math.h>

// Pair-embedding scorer; 4 stacked Linears, no activation => one affine map.
//   v4 = W4[:,0]; v3 = W3@v4; v2 = W2@v3; v1 = W1@v2
//   c  = b4 + b3.v4 + b2.v3 + b1.v2
//   sA[e] = feature[e] . v1[:901];  sB[e] = feature[e] . v1[901:]
//   out[i] = sigmoid(sA[p0] + sB[p1] + c)
//
// Round-3 lesson: cg grid.sync ~60us each -> plain launches.
// Round-4 lesson: per-block redundant v3 as 128 SERIAL wave-iterations on a
//   small grid = 75us latency chain. This round's kAB recomputes v3 per block
//   but THREAD-parallel (256 thr x 2 rows x 16 float4 FMA, W3 L2-hot): short.
// Round-5 (this): fuse kA+kB -> 4 launches (one serial edge removed);
//   kD grid 768->1024 blocks (even 4 blocks/CU, 4-5 rows/wave, makespan
//   80 rows/CU vs 84).
//
// 4 launches: kAB (v2, c init), kC (v1, c+=), kD (72MB stream), kE (head).
// c ordering is stream-ordered (kAB stores c; kC atomicAdds; kE reads).
//
// ws layout (floats): [512,1536) v2 | [1536,3338) v1 | [3400] c
//                     [4096,24096) sA | [24096,44096) sB

#define NTHR 256

__device__ inline float wave_reduce_sum(float v) {
    #pragma unroll
    for (int off = 32; off; off >>= 1) v += __shfl_down(v, off, 64);
    return v;
}

// ---- kAB: per-block v3 = W3@v4 in LDS, then wave-per-row v2 = W2@v3.
//      gwave 1024: c = b4 + b3.v4 + b2.v3 ----
__global__ __launch_bounds__(NTHR)
void kAB(const float* __restrict__ W3, const float* __restrict__ b3,
         const float* __restrict__ W4, const float* __restrict__ b4,
         const float* __restrict__ W2, const float* __restrict__ b2,
         float* __restrict__ v2, float* __restrict__ c) {
    __shared__ __align__(16) float v4s[64];
    __shared__ __align__(16) float v3s[512];
    const int t = threadIdx.x;
    if (t < 64) v4s[t] = W4[t];
    __syncthreads();
    // v3 rows t and t+256: 64-float dot, 16 float4 FMAs each. W3 is 128 KB,
    // L2-hot after the first blocks touch it; v4s reads are LDS broadcast.
    #pragma unroll
    for (int rr = 0; rr < 2; ++rr) {
        const int r = t + 256 * rr;
        const float4* row = (const float4*)(W3 + (size_t)r * 64);
        const float4* x4  = (const float4*)v4s;
        float acc = 0.f;
        #pragma unroll
        for (int k = 0; k < 16; ++k) {
            float4 w = row[k], x = x4[k];
            acc += w.x * x.x + w.y * x.y + w.z * x.z + w.w * x.w;
        }
        v3s[r] = acc;
    }
    __syncthreads();
    const int gwave = blockIdx.x * 4 + (t >> 6), lane = t & 63;
    const float4* x4 = (const float4*)v3s;
    if (gwave < 1024) {
        const float4* row4 = (const float4*)(W2 + (size_t)gwave * 512);
        float acc = 0.f;
        #pragma unroll
        for (int it = 0; it < 2; ++it) {
            float4 w = row4[lane + 64 * it];
            float4 x = x4[lane + 64 * it];
            acc += w.x * x.x + w.y * x.y + w.z * x.z + w.w * x.w;
        }
        acc = wave_reduce_sum(acc);
        if (lane == 0) v2[gwave] = acc;
    } else if (gwave == 1024) {
        const float4* b2p = (const float4*)b2;
        float acc = (lane == 0) ? *b4 : 0.f;
        acc += b3[lane] * v4s[lane];                 // b3.v4 (K=64)
        #pragma unroll
        for (int it = 0; it < 2; ++it) {             // b2.v3 (K=512)
            float4 w = b2p[lane + 64 * it];
            float4 x = x4[lane + 64 * it];
            acc += w.x * x.x + w.y * x.y + w.z * x.z + w.w * x.w;
        }
        acc = wave_reduce_sum(acc);
        if (lane == 0) *c = acc;
    }
}

// ---- kC: v1 = W1@v2 (1802 rows, K=1024: 4 float4/lane); wave 1802: c += b1.v2 ----
__global__ __launch_bounds__(NTHR)
void kC(const float* __restrict__ W1, const float* __restrict__ b1,
        const float* __restrict__ v2, float* __restrict__ v1,
        float* __restrict__ c) {
    const int tid = blockIdx.x * blockDim.x + threadIdx.x;
    const int gwave = tid >> 6, lane = tid & 63;
    if (gwave > 1802) return;
    const float4* row4 = (gwave == 1802) ? (const float4*)b1
                                         : (const float4*)(W1 + (size_t)gwave * 1024);
    const float4* x4 = (const float4*)v2;
    float acc = 0.f;
    #pragma unroll
    for (int it = 0; it < 4; ++it) {
        float4 w = row4[lane + 64 * it];
        float4 x = x4[lane + 64 * it];
        acc += w.x * x.x + w.y * x.y + w.z * x.z + w.w * x.w;
    }
    acc = wave_reduce_sum(acc);
    if (lane == 0) {
        if (gwave == 1802) atomicAdd(c, acc);
        else               v1[gwave] = acc;
    }
}

// ---- kD: per-entity half-dots over the 72 MB feature stream (float4).
// nwave % 4 == 0 and D % 4 == 1 -> per-wave alignment phase constant, so each
// lane's v1 coefficients are fixed; preload once into registers. ----
__global__ __launch_bounds__(NTHR)
void kD(const float* __restrict__ F, const float* __restrict__ v1,
        float* __restrict__ sA, float* __restrict__ sB, int NE, int D) {
    const int tid   = blockIdx.x * blockDim.x + threadIdx.x;
    const int gwave = tid >> 6, lane = tid & 63;
    const int nwave = (gridDim.x * blockDim.x) >> 6;
    const float* va = v1;
    const float* vb = v1 + D;
    const int a0   = (4 - (gwave & 3)) & 3;   // scalars to 16B boundary
    const int nvec = (D - a0) >> 2;
    const int rem  = (D - a0) & 3;

    float ca[16], cb[16];
    #pragma unroll
    for (int it = 0; it < 4; ++it) {
        int vi = lane + 64 * it;
        int d  = a0 + 4 * vi;
        bool ok = vi < nvec;
        ca[4*it+0] = ok ? va[d+0] : 0.f;  cb[4*it+0] = ok ? vb[d+0] : 0.f;
        ca[4*it+1] = ok ? va[d+1] : 0.f;  cb[4*it+1] = ok ? vb[d+1] : 0.f;
        ca[4*it+2] = ok ? va[d+2] : 0.f;  cb[4*it+2] = ok ? vb[d+2] : 0.f;
        ca[4*it+3] = ok ? va[d+3] : 0.f;  cb[4*it+3] = ok ? vb[d+3] : 0.f;
    }
    float cpa = (lane < a0) ? va[lane] : 0.f;
    float cpb = (lane < a0) ? vb[lane] : 0.f;
    int   dt  = a0 + 4 * nvec + lane;
    float cta = (lane < rem) ? va[dt] : 0.f;
    float ctb = (lane < rem) ? vb[dt] : 0.f;

    for (int row = gwave; row < NE; row += nwave) {
        const float* p = F + (size_t)row * (size_t)D;
        float a = 0.f, b = 0.f;
        if (lane < a0) { float f = p[lane]; a = f * cpa; b = f * cpb; }
        const float4* p4 = (const float4*)(p + a0);
        #pragma unroll
        for (int it = 0; it < 4; ++it) {
            int vi = lane + 64 * it;
            if (vi < nvec) {
                float4 f = p4[vi];
                a += f.x * ca[4*it+0] + f.y * ca[4*it+1]
                   + f.z * ca[4*it+2] + f.w * ca[4*it+3];
                b += f.x * cb[4*it+0] + f.y * cb[4*it+1]
                   + f.z * cb[4*it+2] + f.w * cb[4*it+3];
            }
        }
        if (lane < rem) { float f = p[a0 + 4 * nvec + lane]; a += f * cta; b += f * ctb; }
        a = wave_reduce_sum(a);
        b = wave_reduce_sum(b);
        if (lane == 0) { sA[row] = a; sB[row] = b; }
    }
}

// ---- kE: out[i] = sigmoid(sA[p0] + sB[p1] + c) ----
__global__ __launch_bounds__(NTHR)
void kE(const int* __restrict__ tr, const int* __restrict__ te,
        const float* __restrict__ sA, const float* __restrict__ sB,
        const float* __restrict__ c, float* __restrict__ out,
        int NTR, int NTE) {
    const int i = blockIdx.x * blockDim.x + threadIdx.x;
    const int n = NTR + NTE;
    if (i >= n) return;
    int2 pr;
    if (i < NTR) pr = ((const int2*)tr)[i];
    else         pr = ((const int2*)te)[i - NTR];
    float x = sA[pr.x] + sB[pr.y] + *c;      // sA/sB = 160 KB, L2-resident
    out[i] = 1.0f / (1.0f + __expf(-x));
}

extern "C" void kernel_launch(void* const* d_in, const int* in_sizes, int n_in,
                              void* d_out, int out_size, void* d_ws, size_t ws_size,
                              hipStream_t stream) {
    const float* F  = (const float*)d_in[0];
    const float* W1 = (const float*)d_in[1];
    const float* b1 = (const float*)d_in[2];
    const float* W2 = (const float*)d_in[3];
    const float* b2 = (const float*)d_in[4];
    const float* W3 = (const float*)d_in[5];
    const float* b3 = (const float*)d_in[6];
    const float* W4 = (const float*)d_in[7];
    const float* b4 = (const float*)d_in[8];
    const int*   tr = (const int*)d_in[9];
    const int*   te = (const int*)d_in[10];
    float*       out = (float*)d_out;
    float*       ws  = (float*)d_ws;

    const int NE = 20000, D = 901;
    const int NTR = in_sizes[9] / 2;    // 100000
    const int NTE = in_sizes[10] / 2;   // 25000

    float* v2 = ws + 512;
    float* v1 = ws + 1536;
    float* c  = ws + 3400;
    float* sA = ws + 4096;
    float* sB = ws + 24096;

    kAB<<<257, NTHR, 0, stream>>>(W3, b3, W4, b4, W2, b2, v2, c);   // 1028 waves
    kC <<<451, NTHR, 0, stream>>>(W1, b1, v2, v1, c);               // 1804 waves
    kD <<<1024, NTHR, 0, stream>>>(F, v1, sA, sB, NE, D);           // 4096 waves, 4 blk/CU even
    kE <<<(NTR + NTE + NTHR - 1) / NTHR, NTHR, 0, stream>>>(tr, te, sA, sB, c, out, NTR, NTE);
}

// Round 2
// 144.049 us; speedup vs baseline: 1.0329x; 1.0329x over previous
//
#include <hip/hip_runtime.h>
#include <math.h>

// Pair-embedding scorer; 4 stacked Linears, no activation => one affine map.
//   v4 = W4[:,0]; v3 = W3@v4; v2 = W2@v3; v1 = W1@v2
//   c  = b4 + b3.v4 + b2.v3 + b1.v2
//   sA[e] = feature[e] . v1[:901];  sB[e] = feature[e] . v1[901:]
//   out[i] = sigmoid(sA[p0] + sB[p1] + c)
//
// Round-3 lesson: cg grid.sync ~60us each -> plain launches.
// Round-4 lesson: per-block redundant v3 = serial latency chain -> one wave
//   per row, one memory round-trip per wave, full-grid parallelism.
// Round-5 lesson (prev round): 5->4 launches = +2.4us (noise). Launch edges
//   are ~free in this harness; top-5 dispatches are harness 288MB poison
//   fills (~44us each). Kernel-side total ~20-25us of the 148.8 measured.
// Round-6 (this): revert kAB fusion (redundant W3 L2 storm, suspected ~2-3us
//   regression) to proven kA+kB; keep kD at 1024 blocks (even 4 blk/CU,
//   makespan 80 rows/CU vs 84 at 768); kE 2 pairs/thread (int4 loads,
//   float2 stores). Math bit-identical (absmax 0.0 preserved).
//
// 5 launches: kA (v3, c init), kB (v2, c+=), kC (v1, c+=), kD (72MB stream),
// kE (head). c ordering is stream-ordered (each kernel's atomicAdd happens
// before the next launch reads it; kE is the only reader).
//
// ws layout (floats): [0,512) v3 | [512,1536) v2 | [1536,3338) v1 | [3400] c
//                     [4096,24096) sA | [24096,44096) sB

#define NTHR 256

__device__ inline float wave_reduce_sum(float v) {
    #pragma unroll
    for (int off = 32; off; off >>= 1) v += __shfl_down(v, off, 64);
    return v;
}

// ---- kA: v3 = W3@v4 (512 rows, K=64: one element/lane, ONE load/wave).
//      wave 512: c = b4 + b3.v4 ----
__global__ __launch_bounds__(NTHR)
void kA(const float* __restrict__ W3, const float* __restrict__ b3,
        const float* __restrict__ W4, const float* __restrict__ b4,
        float* __restrict__ v3, float* __restrict__ c) {
    const int tid = blockIdx.x * blockDim.x + threadIdx.x;
    const int gwave = tid >> 6, lane = tid & 63;
    if (gwave > 512) return;
    const float x = W4[lane];
    if (gwave == 512) {
        float acc = wave_reduce_sum(b3[lane] * x + ((lane == 0) ? *b4 : 0.f));
        if (lane == 0) *c = acc;
    } else {
        float acc = wave_reduce_sum(W3[(size_t)gwave * 64 + lane] * x);
        if (lane == 0) v3[gwave] = acc;
    }
}

// ---- kB: v2 = W2@v3 (1024 rows, K=512: 2 float4/lane); wave 1024: c += b2.v3 ----
__global__ __launch_bounds__(NTHR)
void kB(const float* __restrict__ W2, const float* __restrict__ b2,
        const float* __restrict__ v3, float* __restrict__ v2,
        float* __restrict__ c) {
    const int tid = blockIdx.x * blockDim.x + threadIdx.x;
    const int gwave = tid >> 6, lane = tid & 63;
    if (gwave > 1024) return;
    if (gwave == 1024) {
        const float4* b4p = (const float4*)b2;
        const float4* x4  = (const float4*)v3;
        float acc = 0.f;
        #pragma unroll
        for (int it = 0; it < 2; ++it) {
            float4 w = b4p[lane + 64 * it];
            float4 x = x4[lane + 64 * it];
            acc += w.x * x.x + w.y * x.y + w.z * x.z + w.w * x.w;
        }
        acc = wave_reduce_sum(acc);
        if (lane == 0) atomicAdd(c, acc);
        return;
    }
    const float4* row4 = (const float4*)(W2 + (size_t)gwave * 512);
    const float4* x4   = (const float4*)v3;
    float acc = 0.f;
    #pragma unroll
    for (int it = 0; it < 2; ++it) {
        float4 w = row4[lane + 64 * it];
        float4 x = x4[lane + 64 * it];
        acc += w.x * x.x + w.y * x.y + w.z * x.z + w.w * x.w;
    }
    acc = wave_reduce_sum(acc);
    if (lane == 0) v2[gwave] = acc;
}

// ---- kC: v1 = W1@v2 (1802 rows, K=1024: 4 float4/lane); wave 1802: c += b1.v2 ----
__global__ __launch_bounds__(NTHR)
void kC(const float* __restrict__ W1, const float* __restrict__ b1,
        const float* __restrict__ v2, float* __restrict__ v1,
        float* __restrict__ c) {
    const int tid = blockIdx.x * blockDim.x + threadIdx.x;
    const int gwave = tid >> 6, lane = tid & 63;
    if (gwave > 1802) return;
    const float4* row4 = (gwave == 1802) ? (const float4*)b1
                                         : (const float4*)(W1 + (size_t)gwave * 1024);
    const float4* x4 = (const float4*)v2;
    float acc = 0.f;
    #pragma unroll
    for (int it = 0; it < 4; ++it) {
        float4 w = row4[lane + 64 * it];
        float4 x = x4[lane + 64 * it];
        acc += w.x * x.x + w.y * x.y + w.z * x.z + w.w * x.w;
    }
    acc = wave_reduce_sum(acc);
    if (lane == 0) {
        if (gwave == 1802) atomicAdd(c, acc);
        else               v1[gwave] = acc;
    }
}

// ---- kD: per-entity half-dots over the 72 MB feature stream (float4).
// nwave % 4 == 0 and D % 4 == 1 -> per-wave alignment phase constant, so each
// lane's v1 coefficients are fixed; preload once into registers.
// 1024 blocks = 4 blocks/CU even; 4096 waves do 4-5 rows each
// (makespan 80 rows/CU vs 84 at 768 blocks). ----
__global__ __launch_bounds__(NTHR)
void kD(const float* __restrict__ F, const float* __restrict__ v1,
        float* __restrict__ sA, float* __restrict__ sB, int NE, int D) {
    const int tid   = blockIdx.x * blockDim.x + threadIdx.x;
    const int gwave = tid >> 6, lane = tid & 63;
    const int nwave = (gridDim.x * blockDim.x) >> 6;
    const float* va = v1;
    const float* vb = v1 + D;
    const int a0   = (4 - (gwave & 3)) & 3;   // scalars to 16B boundary
    const int nvec = (D - a0) >> 2;
    const int rem  = (D - a0) & 3;

    float ca[16], cb[16];
    #pragma unroll
    for (int it = 0; it < 4; ++it) {
        int vi = lane + 64 * it;
        int d  = a0 + 4 * vi;
        bool ok = vi < nvec;
        ca[4*it+0] = ok ? va[d+0] : 0.f;  cb[4*it+0] = ok ? vb[d+0] : 0.f;
        ca[4*it+1] = ok ? va[d+1] : 0.f;  cb[4*it+1] = ok ? vb[d+1] : 0.f;
        ca[4*it+2] = ok ? va[d+2] : 0.f;  cb[4*it+2] = ok ? vb[d+2] : 0.f;
        ca[4*it+3] = ok ? va[d+3] : 0.f;  cb[4*it+3] = ok ? vb[d+3] : 0.f;
    }
    float cpa = (lane < a0) ? va[lane] : 0.f;
    float cpb = (lane < a0) ? vb[lane] : 0.f;
    int   dt  = a0 + 4 * nvec + lane;
    float cta = (lane < rem) ? va[dt] : 0.f;
    float ctb = (lane < rem) ? vb[dt] : 0.f;

    for (int row = gwave; row < NE; row += nwave) {
        const float* p = F + (size_t)row * (size_t)D;
        float a = 0.f, b = 0.f;
        if (lane < a0) { float f = p[lane]; a = f * cpa; b = f * cpb; }
        const float4* p4 = (const float4*)(p + a0);
        #pragma unroll
        for (int it = 0; it < 4; ++it) {
            int vi = lane + 64 * it;
            if (vi < nvec) {
                float4 f = p4[vi];
                a += f.x * ca[4*it+0] + f.y * ca[4*it+1]
                   + f.z * ca[4*it+2] + f.w * ca[4*it+3];
                b += f.x * cb[4*it+0] + f.y * cb[4*it+1]
                   + f.z * cb[4*it+2] + f.w * cb[4*it+3];
            }
        }
        if (lane < rem) { float f = p[a0 + 4 * nvec + lane]; a += f * cta; b += f * ctb; }
        a = wave_reduce_sum(a);
        b = wave_reduce_sum(b);
        if (lane == 0) { sA[row] = a; sB[row] = b; }
    }
}

// ---- kE: out[i] = sigmoid(sA[p0] + sB[p1] + c); 2 pairs/thread
// (int4 index loads, float2 stores; NTR and NTE both even). ----
__global__ __launch_bounds__(NTHR)
void kE(const int* __restrict__ tr, const int* __restrict__ te,
        const float* __restrict__ sA, const float* __restrict__ sB,
        const float* __restrict__ c, float* __restrict__ out,
        int NTR, int NTE) {
    const int j = blockIdx.x * blockDim.x + threadIdx.x;  // pair-pair index
    const int nh = (NTR + NTE) >> 1;
    if (j >= nh) return;
    const float cc = *c;
    int4 q;
    int o;                                    // output element index (even)
    if (j < (NTR >> 1)) { q = ((const int4*)tr)[j];            o = 2 * j; }
    else                { q = ((const int4*)te)[j - (NTR >> 1)]; o = 2 * j; }
    float x0 = sA[q.x] + sB[q.y] + cc;        // sA/sB = 160 KB, L2-resident
    float x1 = sA[q.z] + sB[q.w] + cc;
    float2 r;
    r.x = 1.0f / (1.0f + __expf(-x0));
    r.y = 1.0f / (1.0f + __expf(-x1));
    *(float2*)(out + o) = r;
}

extern "C" void kernel_launch(void* const* d_in, const int* in_sizes, int n_in,
                              void* d_out, int out_size, void* d_ws, size_t ws_size,
                              hipStream_t stream) {
    const float* F  = (const float*)d_in[0];
    const float* W1 = (const float*)d_in[1];
    const float* b1 = (const float*)d_in[2];
    const float* W2 = (const float*)d_in[3];
    const float* b2 = (const float*)d_in[4];
    const float* W3 = (const float*)d_in[5];
    const float* b3 = (const float*)d_in[6];
    const float* W4 = (const float*)d_in[7];
    const float* b4 = (const float*)d_in[8];
    const int*   tr = (const int*)d_in[9];
    const int*   te = (const int*)d_in[10];
    float*       out = (float*)d_out;
    float*       ws  = (float*)d_ws;

    const int NE = 20000, D = 901;
    const int NTR = in_sizes[9] / 2;    // 100000
    const int NTE = in_sizes[10] / 2;   // 25000

    float* v3 = ws;
    float* v2 = ws + 512;
    float* v1 = ws + 1536;
    float* c  = ws + 3400;
    float* sA = ws + 4096;
    float* sB = ws + 24096;

    kA<<<129, NTHR, 0, stream>>>(W3, b3, W4, b4, v3, c);          // 516 waves
    kB<<<257, NTHR, 0, stream>>>(W2, b2, v3, v2, c);              // 1028 waves
    kC<<<451, NTHR, 0, stream>>>(W1, b1, v2, v1, c);              // 1804 waves
    kD<<<1024, NTHR, 0, stream>>>(F, v1, sA, sB, NE, D);          // 4096 waves, 4 blk/CU even
    const int nh = (NTR + NTE) / 2;                               // 62500 thread tasks
    kE<<<(nh + NTHR - 1) / NTHR, NTHR, 0, stream>>>(tr, te, sA, sB, c, out, NTR, NTE);
}